// Round 21
// baseline (219.922 us; speedup 1.0000x reference)
//
#include <hip/hip_runtime.h>
#include <hip/hip_cooperative_groups.h>
#include <math.h>

#define BB 4
#define LL 1024
#define DD 1024
#define KK 20
#define CC 21
#define LC (LL * CC)          // 21504 floats per (b, i) output row-panel
#define NQ (LC / 4)           // 5376 float4 per panel
#define XS 1032               // xT row stride in bf16 elems (1024 + 8 pad)

namespace cg = cooperative_groups;

typedef float vf4    __attribute__((ext_vector_type(4)));
typedef short bf16x8 __attribute__((ext_vector_type(8)));  // MFMA A/B frag (8 bf16)
typedef float f32x4  __attribute__((ext_vector_type(4)));  // MFMA C/D frag

__device__ __forceinline__ unsigned short f2bf(float f) {  // RNE f32->bf16
    unsigned int u = __builtin_bit_cast(unsigned int, f);
    u += 0x7FFFu + ((u >> 16) & 1u);
    return (unsigned short)(u >> 16);
}

__device__ __forceinline__ float wave_reduce_sum(float v) {
    #pragma unroll
    for (int off = 1; off < 64; off <<= 1)
        v += __shfl_xor(v, off, 64);
    return v;
}

#define DOT4(a, b) ((a).x*(b).x + (a).y*(b).y + (a).z*(b).z + (a).w*(b).w)

// ===========================================================================
// FUSED cooperative kernel: 256 blocks x 512 thr (launch verified in R20).
//   P0: zd/M + Wcat. P1: 16-row MFMA tile (verified). P2: 16 panels,
//   it-OUTER / panel-INNER (1 live float4 -> no register cache to spill,
//   lz read exactly once; R20's 52-VGPR re-load pathology eliminated).
// ===========================================================================
__global__ __launch_bounds__(512, 2) void fused_all(
    const float* __restrict__ x,
    const float* __restrict__ dic,
    const float* __restrict__ prior,
    const float* __restrict__ Wy_w, const float* __restrict__ Wy_b,
    const float* __restrict__ Wz_w, const float* __restrict__ Wz_b,
    const float* __restrict__ cs_w, const float* __restrict__ cs_b,
    float* __restrict__ zd, float* __restrict__ M,
    unsigned short* __restrict__ Wcat,
    float* __restrict__ ly_ws, float* __restrict__ lz_ws,
    float* __restrict__ out)
{
    cg::grid_group grid = cg::this_grid();

    const int tid  = threadIdx.x;
    const int blk  = blockIdx.x;        // 0..255
    const int wid  = tid >> 6;          // 0..7
    const int lane = tid & 63;

    __shared__ float zds[KK * CC];
    __shared__ float Ms[KK * CC];
    __shared__ float pr[KK];
    __shared__ float bias[2 * CC];          // [0..20]=Wy_b, [21..41]=cs_b
    __shared__ unsigned short xT[16 * XS];  // 33 KB bf16
    __shared__ float pacc[8 * 16 * 49];     // 25 KB
    __shared__ vf4 lyp4[16 * CC];           // 5.4 KB (P2 pattern table)

    // ================= P0: zd/M dots + Wcat build =================
    {
        int g = blk * 8 + wid;              // 0..2047; need 0..863
        if (g < KK * CC * 2) {
            bool isM = (g >= KK * CC);
            int e2 = isM ? g - KK * CC : g;
            int k = e2 / CC, c = e2 % CC;
            const float4* a4 = reinterpret_cast<const float4*>(dic + (size_t)k * DD);
            const float*  w  = isM ? (cs_w + (size_t)c * (2 * DD) + DD) : (Wz_w + (size_t)c * DD);
            const float4* w4 = reinterpret_cast<const float4*>(w);
            float p = 0.f;
            #pragma unroll
            for (int i = 0; i < 4; ++i) {
                float4 av = a4[lane + 64 * i];
                float4 wv = w4[lane + 64 * i];
                p += DOT4(av, wv);
            }
            p = wave_reduce_sum(p);
            if (lane == 0) {
                if (isM) M[e2] = p;
                else     zd[e2] = p + Wz_b[c];
            }
        } else if (g < KK * CC * 2 + 24) {
            int e2 = g - KK * CC * 2;       // 0..23, each converts 2048 elems
            int base = e2 * 2048;
            #pragma unroll
            for (int t = 0; t < 32; ++t) {
                int i = base + lane + 64 * t;
                int c = i >> 10, k = i & 1023;
                float v;
                if (c < CC)          v = Wy_w[(size_t)c * DD + k];
                else if (c < 2 * CC) v = cs_w[(size_t)(c - CC) * (2 * DD) + k];
                else                 v = 0.f;
                Wcat[i] = f2bf(v);
            }
        }
    }
    __threadfence();
    grid.sync();

    // ================= P1: 16-row MFMA tile (verified layout) ================
    {
        const int fr = lane & 15;
        const int kg = lane >> 4;
        const int r0 = blk * 16;

        for (int i = tid; i < KK * CC; i += 512) { zds[i] = zd[i]; Ms[i] = M[i]; }
        if (tid < KK) pr[tid] = prior[tid];
        if (tid < CC) { bias[tid] = Wy_b[tid]; bias[CC + tid] = cs_b[tid]; }

        // stage 16 rows f32 -> bf16, coalesced: 4096 float4 / 512 thr
        #pragma unroll
        for (int i = 0; i < 8; ++i) {
            int f = tid + i * 512;          // 0..4095
            int row  = f >> 8;              // 256 float4 per row -> 0..15
            int col4 = f & 255;
            float4 v = *reinterpret_cast<const float4*>(x + (size_t)(r0 + row) * DD + col4 * 4);
            unsigned int lo = (unsigned int)f2bf(v.x) | ((unsigned int)f2bf(v.y) << 16);
            unsigned int hi = (unsigned int)f2bf(v.z) | ((unsigned int)f2bf(v.w) << 16);
            *reinterpret_cast<uint2*>(&xT[row * XS + col4 * 4]) = make_uint2(lo, hi);
        }
        __syncthreads();

        const int kbase = wid * 128;        // 8 waves x K=128
        const unsigned short* w0p = Wcat + (size_t)(fr +  0) * DD + kbase + kg * 8;
        const unsigned short* w1p = Wcat + (size_t)(fr + 16) * DD + kbase + kg * 8;
        const unsigned short* w2p = Wcat + (size_t)(fr + 32) * DD + kbase + kg * 8;
        const unsigned short* ap  = &xT[fr * XS + kbase + kg * 8];

        f32x4 acc0 = {0.f, 0.f, 0.f, 0.f};
        f32x4 acc1 = {0.f, 0.f, 0.f, 0.f};
        f32x4 acc2 = {0.f, 0.f, 0.f, 0.f};

        #pragma unroll
        for (int ks = 0; ks < 4; ++ks) {
            bf16x8 af = *reinterpret_cast<const bf16x8*>(ap + ks * 32);
            bf16x8 b0 = *reinterpret_cast<const bf16x8*>(w0p + ks * 32);
            bf16x8 b1 = *reinterpret_cast<const bf16x8*>(w1p + ks * 32);
            bf16x8 b2 = *reinterpret_cast<const bf16x8*>(w2p + ks * 32);
            acc0 = __builtin_amdgcn_mfma_f32_16x16x32_bf16(af, b0, acc0, 0, 0, 0);
            acc1 = __builtin_amdgcn_mfma_f32_16x16x32_bf16(af, b1, acc1, 0, 0, 0);
            acc2 = __builtin_amdgcn_mfma_f32_16x16x32_bf16(af, b2, acc2, 0, 0, 0);
        }

        #pragma unroll
        for (int j = 0; j < 4; ++j) {
            float* pw = pacc + ((wid * 16) + kg * 4 + j) * 49;
            pw[fr]      = acc0[j];
            pw[16 + fr] = acc1[j];
            pw[32 + fr] = acc2[j];
        }
        __syncthreads();

        for (int o = tid; o < 768; o += 512) {
            int row = o / 48, col = o % 48;
            float s = 0.f;
            #pragma unroll
            for (int w = 0; w < 8; ++w) s += pacc[((w * 16) + row) * 49 + col];
            pacc[row * 49 + col] = s;
        }
        __syncthreads();

        if (tid < 64) {
            const float* f = pacc + fr * 49;
            const float scale = 0.21821789023599238f;   // 1/sqrt(21)
            float s[KK];
            float m = -1e30f;
            #pragma unroll
            for (int k = 0; k < KK; ++k) {
                float t = 0.f;
                #pragma unroll
                for (int c = 0; c < CC; ++c) t += (f[c] + bias[c]) * zds[k * CC + c];
                s[k] = t * scale;
                m = fmaxf(m, s[k]);
            }
            float sum = 0.f;
            #pragma unroll
            for (int k = 0; k < KK; ++k) { s[k] = expf(s[k] - m); sum += s[k]; }
            float inv = 1.f / sum;
            float wk[KK];
            #pragma unroll
            for (int k = 0; k < KK; ++k) wk[k] = s[k] * inv * pr[k];

            size_t rr = (size_t)(r0 + fr);
            for (int c = kg; c < CC; c += 4) {
                float lzv = bias[CC + c];               // cs_b
                #pragma unroll
                for (int k = 0; k < KK; ++k) lzv += wk[k] * Ms[k * CC + c];
                ly_ws[rr * CC + c] = f[CC + c];         // cols 21..41 = ly
                lz_ws[rr * CC + c] = lzv;
            }
        }
    }
    __threadfence();
    grid.sync();

    // ===== P2: outer-sum write, it-OUTER / panel-INNER (no reg cache) =======
    {
        const int b  = blk >> 6;            // 64 blocks per image
        const int i0 = (blk & 63) << 4;     // 16 panels

        {
            float* lyp = reinterpret_cast<float*>(lyp4);
            for (int i2 = tid; i2 < 16 * 84; i2 += 512) {
                int i = i2 / 84, f = i2 % 84;
                lyp[i * 84 + f] = ly_ws[(size_t)(b * LL + i0 + i) * CC + (f % 21)];
            }
        }
        __syncthreads();

        const float* lzp = lz_ws + (size_t)b * LC;
        float* outbase = out + (size_t)(b * LL + i0) * LC;

        int g = tid % 21;                   // g == idx mod 21; step 512 -> +8 mod 21
        for (int it = 0; it < 11; ++it) {
            int idx = tid + it * 512;
            if (idx < NQ) {
                vf4 lz4 = *reinterpret_cast<const vf4*>(lzp + (size_t)idx * 4);
                #pragma unroll
                for (int i = 0; i < 16; ++i) {
                    *reinterpret_cast<vf4*>(outbase + (size_t)i * LC + (size_t)idx * 4)
                        = lz4 + lyp4[i * CC + g];
                }
            }
            g += 8; if (g >= 21) g -= 21;
        }
    }
}

// ===========================================================================
// FALLBACK path (verified R18 pipeline, 101.5 us) — only if coop rejected.
// ===========================================================================
__global__ __launch_bounds__(64) void k0_zdM(
    const float* __restrict__ dic,
    const float* __restrict__ Wz_w, const float* __restrict__ Wz_b,
    const float* __restrict__ cs_w, const float* __restrict__ Wy_w,
    float* __restrict__ zd, float* __restrict__ M,
    unsigned short* __restrict__ Wcat)
{
    int blk = blockIdx.x;
    int lane = threadIdx.x;

    if (blk < 2 * KK * CC) {
        bool isM = (blk >= KK * CC);
        int e2 = isM ? blk - KK * CC : blk;
        int k = e2 / CC, c = e2 % CC;
        const float4* a4 = reinterpret_cast<const float4*>(dic + (size_t)k * DD);
        const float*  w  = isM ? (cs_w + (size_t)c * (2 * DD) + DD) : (Wz_w + (size_t)c * DD);
        const float4* w4 = reinterpret_cast<const float4*>(w);
        float p = 0.f;
        #pragma unroll
        for (int i = 0; i < 4; ++i) {
            float4 av = a4[lane + 64 * i];
            float4 wv = w4[lane + 64 * i];
            p += DOT4(av, wv);
        }
        p = wave_reduce_sum(p);
        if (lane == 0) {
            if (isM) M[e2] = p;
            else     zd[e2] = p + Wz_b[c];
        }
    } else {
        int e2 = blk - 2 * KK * CC;
        int base = e2 * 2048;
        #pragma unroll
        for (int t = 0; t < 32; ++t) {
            int i = base + lane + 64 * t;
            int c = i >> 10, k = i & 1023;
            float v;
            if (c < CC)          v = Wy_w[(size_t)c * DD + k];
            else if (c < 2 * CC) v = cs_w[(size_t)(c - CC) * (2 * DD) + k];
            else                 v = 0.f;
            Wcat[i] = f2bf(v);
        }
    }
}

__global__ __launch_bounds__(256) void k1_mfma(
    const float* __restrict__ x,
    const float* __restrict__ prior,
    const float* __restrict__ Wy_b, const float* __restrict__ cs_b,
    const unsigned short* __restrict__ Wcat,
    const float* __restrict__ zd, const float* __restrict__ M,
    float* __restrict__ ly_ws, float* __restrict__ lz_ws)
{
    const int tid  = threadIdx.x;
    const int wid  = tid >> 6;
    const int lane = tid & 63;
    const int fr   = lane & 15;
    const int frm  = fr & 7;
    const int kg   = lane >> 4;
    const int r0   = blockIdx.x * 8;

    __shared__ float zds[KK * CC];
    __shared__ float Ms[KK * CC];
    __shared__ float pr[KK];
    __shared__ float bias[2 * CC];
    __shared__ unsigned short xT[8 * XS];
    __shared__ float pacc[4 * 8 * 49];

    for (int i = tid; i < KK * CC; i += 256) { zds[i] = zd[i]; Ms[i] = M[i]; }
    if (tid < KK) pr[tid] = prior[tid];
    if (tid < CC) { bias[tid] = Wy_b[tid]; bias[CC + tid] = cs_b[tid]; }

    #pragma unroll
    for (int i = 0; i < 8; ++i) {
        int f = tid + i * 256;
        int row  = f >> 8;
        int col4 = f & 255;
        float4 v = *reinterpret_cast<const float4*>(x + (size_t)(r0 + row) * DD + col4 * 4);
        unsigned int lo = (unsigned int)f2bf(v.x) | ((unsigned int)f2bf(v.y) << 16);
        unsigned int hi = (unsigned int)f2bf(v.z) | ((unsigned int)f2bf(v.w) << 16);
        *reinterpret_cast<uint2*>(&xT[row * XS + col4 * 4]) = make_uint2(lo, hi);
    }
    __syncthreads();

    const int kbase = wid * 256;
    const unsigned short* w0p = Wcat + (size_t)(fr +  0) * DD + kbase + kg * 8;
    const unsigned short* w1p = Wcat + (size_t)(fr + 16) * DD + kbase + kg * 8;
    const unsigned short* w2p = Wcat + (size_t)(fr + 32) * DD + kbase + kg * 8;
    const unsigned short* ap  = &xT[frm * XS + kbase + kg * 8];

    f32x4 acc0 = {0.f, 0.f, 0.f, 0.f};
    f32x4 acc1 = {0.f, 0.f, 0.f, 0.f};
    f32x4 acc2 = {0.f, 0.f, 0.f, 0.f};

    #pragma unroll
    for (int ks = 0; ks < 8; ++ks) {
        bf16x8 af = *reinterpret_cast<const bf16x8*>(ap + ks * 32);
        bf16x8 b0 = *reinterpret_cast<const bf16x8*>(w0p + ks * 32);
        bf16x8 b1 = *reinterpret_cast<const bf16x8*>(w1p + ks * 32);
        bf16x8 b2 = *reinterpret_cast<const bf16x8*>(w2p + ks * 32);
        acc0 = __builtin_amdgcn_mfma_f32_16x16x32_bf16(af, b0, acc0, 0, 0, 0);
        acc1 = __builtin_amdgcn_mfma_f32_16x16x32_bf16(af, b1, acc1, 0, 0, 0);
        acc2 = __builtin_amdgcn_mfma_f32_16x16x32_bf16(af, b2, acc2, 0, 0, 0);
    }

    if (kg < 2) {
        #pragma unroll
        for (int j = 0; j < 4; ++j) {
            float* pw = pacc + ((wid * 8) + kg * 4 + j) * 49;
            pw[fr]      = acc0[j];
            pw[16 + fr] = acc1[j];
            pw[32 + fr] = acc2[j];
        }
    }
    __syncthreads();

    for (int o = tid; o < 384; o += 256) {
        int row = o / 48, col = o % 48;
        float s = pacc[row * 49 + col]
                + pacc[(8  + row) * 49 + col]
                + pacc[(16 + row) * 49 + col]
                + pacc[(24 + row) * 49 + col];
        pacc[row * 49 + col] = s;
    }
    __syncthreads();

    if (tid < 64) {
        const int r = tid & 7;
        const int g = tid >> 3;
        const float* f = pacc + r * 49;
        const float scale = 0.21821789023599238f;
        float s[KK];
        float m = -1e30f;
        #pragma unroll
        for (int k = 0; k < KK; ++k) {
            float t = 0.f;
            #pragma unroll
            for (int c = 0; c < CC; ++c) t += (f[c] + bias[c]) * zds[k * CC + c];
            s[k] = t * scale;
            m = fmaxf(m, s[k]);
        }
        float sum = 0.f;
        #pragma unroll
        for (int k = 0; k < KK; ++k) { s[k] = expf(s[k] - m); sum += s[k]; }
        float inv = 1.f / sum;
        float wk[KK];
        #pragma unroll
        for (int k = 0; k < KK; ++k) wk[k] = s[k] * inv * pr[k];

        size_t rr = (size_t)(r0 + r);
        for (int c = g; c < CC; c += 8) {
            float lzv = bias[CC + c];
            #pragma unroll
            for (int k = 0; k < KK; ++k) lzv += wk[k] * Ms[k * CC + c];
            ly_ws[rr * CC + c] = f[CC + c];
            lz_ws[rr * CC + c] = lzv;
        }
    }
}

__global__ __launch_bounds__(512) void k2_outer(
    const float* __restrict__ ly_ws, const float* __restrict__ lz_ws,
    float* __restrict__ out)
{
    int tid = threadIdx.x;
    int blk = blockIdx.x;
    int b  = blk >> 8;
    int i0 = (blk & 255) << 2;

    __shared__ vf4 lyp4[4 * CC];
    {
        float* lyp = reinterpret_cast<float*>(lyp4);
        if (tid < 4 * 84) {
            int i = tid / 84, f = tid % 84;
            lyp[i * 84 + f] = ly_ws[(size_t)(b * LL + i0 + i) * CC + (f % 21)];
        }
    }
    const float* lzp = lz_ws + (size_t)b * LC;
    vf4 lzv[11];
    #pragma unroll
    for (int it = 0; it < 11; ++it) {
        int idx = tid + it * 512;
        lzv[it] = (idx < NQ) ? *reinterpret_cast<const vf4*>(lzp + (size_t)idx * 4)
                             : (vf4){0.f, 0.f, 0.f, 0.f};
    }
    __syncthreads();
    int g0 = tid % 21;

    #pragma unroll
    for (int i = 0; i < 4; ++i) {
        float* op = out + (size_t)(b * LL + i0 + i) * LC;
        const vf4* lyp_i = lyp4 + i * CC;
        int g = g0;
        #pragma unroll
        for (int it = 0; it < 11; ++it) {
            int idx = tid + it * 512;
            if (idx < NQ) {
                *reinterpret_cast<vf4*>(op + (size_t)idx * 4) = lzv[it] + lyp_i[g];
            }
            g += 8; if (g >= 21) g -= 21;
        }
    }
}

extern "C" void kernel_launch(void* const* d_in, const int* in_sizes, int n_in,
                              void* d_out, int out_size, void* d_ws, size_t ws_size,
                              hipStream_t stream)
{
    const float* x     = (const float*)d_in[0];
    const float* dic   = (const float*)d_in[1];
    const float* prior = (const float*)d_in[2];
    const float* Wy_w  = (const float*)d_in[3];
    const float* Wy_b  = (const float*)d_in[4];
    const float* Wz_w  = (const float*)d_in[5];
    const float* Wz_b  = (const float*)d_in[6];
    const float* cs_w  = (const float*)d_in[7];
    const float* cs_b  = (const float*)d_in[8];
    float* out = (float*)d_out;

    float* ws = (float*)d_ws;
    float* zd = ws;                       // 420 floats
    float* M  = ws + 512;                 // 420 floats
    float* ly = ws + 1024;                // B*L*C = 86016 floats
    float* lz = ly + BB * LL * CC;        // 86016 floats
    unsigned short* Wcat = (unsigned short*)(ws + 1024 + 2 * BB * LL * CC);  // 48*1024 bf16

    void* args[] = {
        (void*)&x, (void*)&dic, (void*)&prior,
        (void*)&Wy_w, (void*)&Wy_b, (void*)&Wz_w, (void*)&Wz_b,
        (void*)&cs_w, (void*)&cs_b,
        (void*)&zd, (void*)&M, (void*)&Wcat,
        (void*)&ly, (void*)&lz, (void*)&out
    };
    hipError_t err = hipLaunchCooperativeKernel((void*)fused_all, dim3(256), dim3(512),
                                                args, 0, stream);
    if (err != hipSuccess) {
        // verified 3-kernel fallback (R18: 101.5 us)
        k0_zdM <<<dim3(2 * KK * CC + 24), dim3(64),  0, stream>>>(dic, Wz_w, Wz_b, cs_w, Wy_w,
                                                                  zd, M, Wcat);
        k1_mfma<<<dim3(BB * LL / 8),      dim3(256), 0, stream>>>(x, prior, Wy_b, cs_b, Wcat,
                                                                  zd, M, ly, lz);
        k2_outer<<<dim3(BB * LL / 4),     dim3(512), 0, stream>>>(ly, lz, out);
    }
}

// Round 22
// 90.235 us; speedup vs baseline: 2.4372x; 2.4372x over previous
//
#include <hip/hip_runtime.h>
#include <math.h>

#define BB 4
#define LL 1024
#define DD 1024
#define KK 20
#define CC 21
#define LC (LL * CC)          // 21504 floats per (b, i) output row-panel
#define NQ (LC / 4)           // 5376 float4 per panel

typedef float vf4    __attribute__((ext_vector_type(4)));
typedef short bf16x8 __attribute__((ext_vector_type(8)));  // MFMA A/B frag (8 bf16)
typedef float f32x4  __attribute__((ext_vector_type(4)));  // MFMA C/D frag

__device__ __forceinline__ unsigned short f2bf(float f) {  // RNE f32->bf16
    unsigned int u = __builtin_bit_cast(unsigned int, f);
    u += 0x7FFFu + ((u >> 16) & 1u);
    return (unsigned short)(u >> 16);
}

__device__ __forceinline__ bf16x8 cvt8(float4 a, float4 b) {
    bf16x8 r;
    r[0] = (short)f2bf(a.x); r[1] = (short)f2bf(a.y);
    r[2] = (short)f2bf(a.z); r[3] = (short)f2bf(a.w);
    r[4] = (short)f2bf(b.x); r[5] = (short)f2bf(b.y);
    r[6] = (short)f2bf(b.z); r[7] = (short)f2bf(b.w);
    return r;
}

// fire-and-forget 16B/lane global->LDS DMA (wave-uniform LDS base + lane*16)
__device__ __forceinline__ void gload_lds16(const float* g, float* l) {
    __builtin_amdgcn_global_load_lds(
        (const __attribute__((address_space(1))) unsigned int*)g,
        (__attribute__((address_space(3))) unsigned int*)l, 16, 0, 0);
}

__device__ __forceinline__ float wave_reduce_sum(float v) {
    #pragma unroll
    for (int off = 1; off < 64; off <<= 1)
        v += __shfl_xor(v, off, 64);
    return v;
}

#define DOT4(a, b) ((a).x*(b).x + (a).y*(b).y + (a).z*(b).z + (a).w*(b).w)

// ---------------------------------------------------------------------------
// Kernel 0 (zd/M only — Wcat eliminated): 840 one-wave blocks, float4 dots.
// ---------------------------------------------------------------------------
__global__ __launch_bounds__(64) void k0_zdM(
    const float* __restrict__ dic,
    const float* __restrict__ Wz_w, const float* __restrict__ Wz_b,
    const float* __restrict__ cs_w,
    float* __restrict__ zd, float* __restrict__ M)
{
    int blk = blockIdx.x;               // 0..839
    int lane = threadIdx.x;
    bool isM = (blk >= KK * CC);
    int e2 = isM ? blk - KK * CC : blk;
    int k = e2 / CC, c = e2 % CC;
    const float4* a4 = reinterpret_cast<const float4*>(dic + (size_t)k * DD);
    const float*  w  = isM ? (cs_w + (size_t)c * (2 * DD) + DD) : (Wz_w + (size_t)c * DD);
    const float4* w4 = reinterpret_cast<const float4*>(w);
    float p = 0.f;
    #pragma unroll
    for (int i = 0; i < 4; ++i) {
        float4 av = a4[lane + 64 * i];
        float4 wv = w4[lane + 64 * i];
        p += DOT4(av, wv);
    }
    p = wave_reduce_sum(p);
    if (lane == 0) {
        if (isM) M[e2] = p;
        else     zd[e2] = p + Wz_b[c];
    }
}

// ---------------------------------------------------------------------------
// Kernel 1 (R14 v7 + on-the-fly B conversion, no Wcat): 256 blocks x 512 thr.
//   Stage x-tile [16][1024] f32 -> linear LDS via gload_lds (R14-verified).
//   B rows r (virtual Wcat rows): r<21 -> Wy_w[r]; 21..41 -> cs_w[r-21][:D];
//   42..47 -> zero. Loaded as f32 float4 x2, cvt->bf16 in-flight
//   (bit-identical to the old Wcat values).
// ---------------------------------------------------------------------------
__global__ __launch_bounds__(512) void k1_mfma(
    const float* __restrict__ x,
    const float* __restrict__ prior,
    const float* __restrict__ Wy_w, const float* __restrict__ Wy_b,
    const float* __restrict__ cs_w, const float* __restrict__ cs_b,
    const float* __restrict__ zd, const float* __restrict__ M,
    float* __restrict__ ly_ws, float* __restrict__ lz_ws)
{
    const int tid  = threadIdx.x;
    const int wid  = tid >> 6;          // 0..7
    const int lane = tid & 63;
    const int fr   = lane & 15;
    const int kg   = lane >> 4;
    const int r0   = blockIdx.x * 16;

    __shared__ float zds[KK * CC];
    __shared__ float Ms[KK * CC];
    __shared__ float pr[KK];
    __shared__ float bias[2 * CC];
    __shared__ float xT[16 * 1024];     // 64 KB, LINEAR (gload_lds requirement)
    __shared__ float pacc[8 * 16 * 49];

    // ---- stage x-tile: 8 fire-and-forget 1KB wave-DMAs per wave ----
    {
        const float* gbase = x + (size_t)r0 * DD;       // 16 rows contiguous
        #pragma unroll
        for (int i = 0; i < 8; ++i) {
            int chunk = wid * 8 + i;                    // 0..63, 256 floats each
            gload_lds16(gbase + chunk * 256 + lane * 4, &xT[chunk * 256]);
        }
    }

    for (int i = tid; i < KK * CC; i += 512) { zds[i] = zd[i]; Ms[i] = M[i]; }
    if (tid < KK) pr[tid] = prior[tid];
    if (tid < CC) { bias[tid] = Wy_b[tid]; bias[CC + tid] = cs_b[tid]; }
    __syncthreads();                    // drains vmcnt (gload_lds) + lds

    // ---- per-lane B row pointers (virtual Wcat rows fr, fr+16, fr+32) ----
    const float* w0p = Wy_w + (size_t)fr * DD;                              // rows 0..15
    const float* w1p = (fr < 5) ? (Wy_w + (size_t)(fr + 16) * DD)           // rows 16..20
                                : (cs_w + (size_t)(fr - 5) * (2 * DD));     // rows 21..31
    const bool  z2  = (fr >= 10);                                           // rows 42..47 = 0
    const float* w2p = z2 ? cs_w                                            // dummy (zeroed)
                          : (cs_w + (size_t)(fr + 11) * (2 * DD));          // rows 32..41

    const int kbase = wid * 128;        // 8 waves x K=128
    const int koff  = kbase + kg * 8;
    const float* ap = &xT[fr * 1024 + koff];

    f32x4 acc0 = {0.f, 0.f, 0.f, 0.f};
    f32x4 acc1 = {0.f, 0.f, 0.f, 0.f};
    f32x4 acc2 = {0.f, 0.f, 0.f, 0.f};

    #pragma unroll
    for (int ks = 0; ks < 4; ++ks) {
        int o = koff + ks * 32;
        float4 a0 = *reinterpret_cast<const float4*>(ap + ks * 32);
        float4 a1 = *reinterpret_cast<const float4*>(ap + ks * 32 + 4);
        float4 b0a = *reinterpret_cast<const float4*>(w0p + o);
        float4 b0b = *reinterpret_cast<const float4*>(w0p + o + 4);
        float4 b1a = *reinterpret_cast<const float4*>(w1p + o);
        float4 b1b = *reinterpret_cast<const float4*>(w1p + o + 4);
        float4 b2a = *reinterpret_cast<const float4*>(w2p + o);
        float4 b2b = *reinterpret_cast<const float4*>(w2p + o + 4);
        if (z2) { b2a = make_float4(0.f,0.f,0.f,0.f); b2b = make_float4(0.f,0.f,0.f,0.f); }
        bf16x8 af = cvt8(a0, a1);
        bf16x8 b0 = cvt8(b0a, b0b);
        bf16x8 b1 = cvt8(b1a, b1b);
        bf16x8 b2 = cvt8(b2a, b2b);
        acc0 = __builtin_amdgcn_mfma_f32_16x16x32_bf16(af, b0, acc0, 0, 0, 0);
        acc1 = __builtin_amdgcn_mfma_f32_16x16x32_bf16(af, b1, acc1, 0, 0, 0);
        acc2 = __builtin_amdgcn_mfma_f32_16x16x32_bf16(af, b2, acc2, 0, 0, 0);
    }

    // D frags -> pacc[wid]: m = kg*4+j (x-row), cols fr / 16+fr / 32+fr
    #pragma unroll
    for (int j = 0; j < 4; ++j) {
        float* pw = pacc + ((wid * 16) + kg * 4 + j) * 49;
        pw[fr]      = acc0[j];
        pw[16 + fr] = acc1[j];
        pw[32 + fr] = acc2[j];
    }
    __syncthreads();

    // cross-wave reduce: 768 outputs, 8-way, thread-owned in-place into w=0
    #pragma unroll
    for (int p = 0; p < 2; ++p) {
        int o = tid + p * 512;
        if (o < 768) {
            int row = o / 48, col = o % 48;
            float s = 0.f;
            #pragma unroll
            for (int w = 0; w < 8; ++w) s += pacc[((w * 16) + row) * 49 + col];
            pacc[row * 49 + col] = s;
        }
    }
    __syncthreads();

    // wave-0 epilogue: softmax for row fr (4-way redundant over kg), lz c=kg::4
    if (tid < 64) {
        const float* f = pacc + fr * 49;
        const float scale = 0.21821789023599238f;   // 1/sqrt(21)
        float s[KK];
        float m = -1e30f;
        #pragma unroll
        for (int k = 0; k < KK; ++k) {
            float t = 0.f;
            #pragma unroll
            for (int c = 0; c < CC; ++c) t += (f[c] + bias[c]) * zds[k * CC + c];
            s[k] = t * scale;
            m = fmaxf(m, s[k]);
        }
        float sum = 0.f;
        #pragma unroll
        for (int k = 0; k < KK; ++k) { s[k] = expf(s[k] - m); sum += s[k]; }
        float inv = 1.f / sum;
        float wk[KK];
        #pragma unroll
        for (int k = 0; k < KK; ++k) wk[k] = s[k] * inv * pr[k];

        size_t rr = (size_t)(r0 + fr);
        for (int c = kg; c < CC; c += 4) {
            float lzv = bias[CC + c];                   // cs_b
            #pragma unroll
            for (int k = 0; k < KK; ++k) lzv += wk[k] * Ms[k * CC + c];
            ly_ws[rr * CC + c] = f[CC + c];             // cols 21..41 = ly
            lz_ws[rr * CC + c] = lzv;
        }
    }
}

// ---------------------------------------------------------------------------
// Kernel 2: outer-sum write — measured 49.3 us at 7.15 TB/s (89% peak).
// ---------------------------------------------------------------------------
__global__ __launch_bounds__(512) void k2_outer(
    const float* __restrict__ ly_ws, const float* __restrict__ lz_ws,
    float* __restrict__ out)
{
    int tid = threadIdx.x;
    int blk = blockIdx.x;               // 0..1023
    int b  = blk >> 8;                  // 256 blocks per image
    int i0 = (blk & 255) << 2;          // * 4 panels

    __shared__ vf4 lyp4[4 * CC];
    {
        float* lyp = reinterpret_cast<float*>(lyp4);
        if (tid < 4 * 84) {
            int i = tid / 84, f = tid % 84;
            lyp[i * 84 + f] = ly_ws[(size_t)(b * LL + i0 + i) * CC + (f % 21)];
        }
    }
    const float* lzp = lz_ws + (size_t)b * LC;
    vf4 lzv[11];
    #pragma unroll
    for (int it = 0; it < 11; ++it) {
        int idx = tid + it * 512;
        lzv[it] = (idx < NQ) ? *reinterpret_cast<const vf4*>(lzp + (size_t)idx * 4)
                             : (vf4){0.f, 0.f, 0.f, 0.f};
    }
    __syncthreads();
    int g0 = tid % 21;                  // (tid + it*512) % 21 steps by +8 mod 21

    #pragma unroll
    for (int i = 0; i < 4; ++i) {
        float* op = out + (size_t)(b * LL + i0 + i) * LC;
        const vf4* lyp_i = lyp4 + i * CC;
        int g = g0;
        #pragma unroll
        for (int it = 0; it < 11; ++it) {
            int idx = tid + it * 512;
            if (idx < NQ) {
                *reinterpret_cast<vf4*>(op + (size_t)idx * 4) = lzv[it] + lyp_i[g];
            }
            g += 8; if (g >= 21) g -= 21;
        }
    }
}

extern "C" void kernel_launch(void* const* d_in, const int* in_sizes, int n_in,
                              void* d_out, int out_size, void* d_ws, size_t ws_size,
                              hipStream_t stream)
{
    const float* x     = (const float*)d_in[0];
    const float* dic   = (const float*)d_in[1];
    const float* prior = (const float*)d_in[2];
    const float* Wy_w  = (const float*)d_in[3];
    const float* Wy_b  = (const float*)d_in[4];
    const float* Wz_w  = (const float*)d_in[5];
    const float* Wz_b  = (const float*)d_in[6];
    const float* cs_w  = (const float*)d_in[7];
    const float* cs_b  = (const float*)d_in[8];
    float* out = (float*)d_out;

    float* ws = (float*)d_ws;
    float* zd = ws;                       // 420 floats
    float* M  = ws + 512;                 // 420 floats
    float* ly = ws + 1024;                // B*L*C = 86016 floats
    float* lz = ly + BB * LL * CC;        // 86016 floats

    k0_zdM <<<dim3(2 * KK * CC),  dim3(64),  0, stream>>>(dic, Wz_w, Wz_b, cs_w, zd, M);
    k1_mfma<<<dim3(BB * LL / 16), dim3(512), 0, stream>>>(x, prior, Wy_w, Wy_b, cs_w, cs_b,
                                                          zd, M, ly, lz);
    k2_outer<<<dim3(BB * LL / 4), dim3(512), 0, stream>>>(ly, lz, out);
}